// Round 4
// baseline (20.199 us; speedup 1.0000x reference)
//
#include <hip/hip_runtime.h>
#include <math.h>
#include <float.h>

#define NEAR_PLANE 0.8f
#define FAR_PLANE 1000.0f
#define ALPHA_SKIP (1.0f/255.0f)
#define ALPHA_CLAMP 0.99f
#define ACC_BREAK 0.9999f

// Two-kernel design.
//
// prep_kernel (ONE block, 256 threads): transform/project each gaussian,
// stable depth order via rank sort (rank = #keys strictly before mine, index
// tie-break == stable jnp.argsort), per-gaussian conic math, then scatter
// raster params to workspace in SORTED order and atomicOr per-tile 256-bit
// coverage masks for the conservative ALPHA_SKIP ellipse bbox
// (quad <= 2*ln(255*sig/den) + margin). Runs once (~2 us) instead of
// redundantly in all 256 raster blocks.
//
// raster_kernel (one block per 16x16 tile): stages the 8 KB sorted param
// table (2 float4 loads/thread) + 4 mask words into LDS, computes K^-1 / SH
// basis while the loads are in flight, then walks only the mask-set gaussians
// front-to-back. Skipped gaussians contribute exactly 0.0f to the cumulative
// sum -> output bit-identical to the dense reference loop.
//
// Assumes N <= 256 (bench: 256) and W,H multiples of 16 (bench: 256x256).
//
// ws layout (float slots):
//   [0..256)     ux     (sorted slot)
//   [256..512)   uy
//   [512..768)   ia
//   [768..1024)  ib
//   [1024..1280) ic
//   [1280..1536) den
//   [1536..1792) sig
//   [1792..2048) gid (int)
//   [2048..4096) per-tile masks: tile*(4 x u64), 8 KB

__global__ __launch_bounds__(256)
void prep_kernel(const float* __restrict__ pts,
                 const float* __restrict__ feats,
                 const float* __restrict__ K,
                 const float* __restrict__ T,
                 const int* __restrict__ Hp,
                 const int* __restrict__ Wp,
                 float* __restrict__ ws,
                 int N) {
    __shared__ float s_key[256];
    const int t  = threadIdx.x;
    const int Wd = *Wp, Hd = *Hp;
    const int tilesX = (Wd + 15) >> 4;
    const int tilesY = (Hd + 15) >> 4;
    unsigned long long* masks = (unsigned long long*)(ws + 2048);

    // zero this call's coverage masks (ws is NOT re-poisoned between replays)
    const int nmw = tilesX * tilesY * 4;
    for (int i = t; i < nmw; i += 256) masks[i] = 0ULL;

    const float R00 = T[0],  R01 = T[1],  R02 = T[2],  ttx = T[3];
    const float R10 = T[4],  R11 = T[5],  R12 = T[6],  tty = T[7];
    const float R20 = T[8],  R21 = T[9],  R22 = T[10], ttz = T[11];

    // ---- transform + project own gaussian (original index t) ----
    float key = FLT_MAX;               // pad slots (t >= N) sort last
    float cxv = 0.f, cyv = 0.f, czv = 1.f, pu = 0.f, pv = 0.f;
    bool in_cam = false;
    if (t < N) {
        const float px = pts[3*t], py = pts[3*t+1], pz = pts[3*t+2];
        cxv = R00*px + R01*py + R02*pz + ttx;
        cyv = R10*px + R11*py + R12*pz + tty;
        czv = R20*px + R21*py + R22*pz + ttz;
        const float zc = czv;
        const float denom = fmaxf(zc, 1e-6f);
        const float K00 = K[0], K01 = K[1], K02 = K[2];
        const float K10 = K[3], K11 = K[4], K12 = K[5];
        pu = (K00*cxv + K01*cyv + K02*czv) / denom;
        pv = (K10*cxv + K11*cyv + K12*czv) / denom;
        in_cam = (zc > NEAR_PLANE) && (zc < FAR_PLANE) &&
                 (pu >= 0.0f) && (pu < (float)Wd) &&
                 (pv >= 0.0f) && (pv < (float)Hd);
        key = in_cam ? zc : 1e10f;
    }
    s_key[t] = key;
    __syncthreads();

    // ---- stable rank sort (batched so 16 LDS b128 loads stay in flight) ----
    int rank = 0;
    {
        const float4* k4 = (const float4*)s_key;
        #pragma unroll 16
        for (int j4 = 0; j4 < 64; ++j4) {
            const float4 kv = k4[j4];
            const int jb = j4 << 2;
            rank += (int)(kv.x < key || (kv.x == key && (jb + 0) < t));
            rank += (int)(kv.y < key || (kv.y == key && (jb + 1) < t));
            rank += (int)(kv.z < key || (kv.z == key && (jb + 2) < t));
            rank += (int)(kv.w < key || (kv.w == key && (jb + 3) < t));
        }
    }

    // ---- conic + cull for own gaussian, scatter to sorted slot ----
    if (in_cam) {
        const float* f = feats + 56*t;
        float qx = f[0], qy = f[1], qz = f[2], qw = f[3];
        const float qn = sqrtf(qx*qx + qy*qy + qz*qz + qw*qw);
        qx /= qn; qy /= qn; qz /= qn; qw /= qn;
        const float Q00 = 1.0f - 2.0f*(qy*qy + qz*qz);
        const float Q01 = 2.0f*(qx*qy - qz*qw);
        const float Q02 = 2.0f*(qx*qz + qy*qw);
        const float Q10 = 2.0f*(qx*qy + qz*qw);
        const float Q11 = 1.0f - 2.0f*(qx*qx + qz*qz);
        const float Q12 = 2.0f*(qy*qz - qx*qw);
        const float Q20 = 2.0f*(qx*qz - qy*qw);
        const float Q21 = 2.0f*(qy*qz + qx*qw);
        const float Q22 = 1.0f - 2.0f*(qx*qx + qy*qy);
        const float s0 = expf(f[4]), s1 = expf(f[5]), s2 = expf(f[6]);
        const float M00 = Q00*s0, M01 = Q01*s1, M02 = Q02*s2;
        const float M10 = Q10*s0, M11 = Q11*s1, M12 = Q12*s2;
        const float M20 = Q20*s0, M21 = Q21*s1, M22 = Q22*s2;
        const float S00 = M00*M00 + M01*M01 + M02*M02;
        const float S01 = M00*M10 + M01*M11 + M02*M12;
        const float S02 = M00*M20 + M01*M21 + M02*M22;
        const float S11 = M10*M10 + M11*M11 + M12*M12;
        const float S12 = M10*M20 + M11*M21 + M12*M22;
        const float S22 = M20*M20 + M21*M21 + M22*M22;

        const float fx = K[0], fy = K[4];
        const float J00 = fx / czv;
        const float J02 = -fx * cxv / (czv * czv);
        const float J11 = fy / czv;
        const float J12 = -fy * cyv / (czv * czv);
        const float W00 = J00*R00 + J02*R20;
        const float W01 = J00*R01 + J02*R21;
        const float W02 = J00*R02 + J02*R22;
        const float W10 = J11*R10 + J12*R20;
        const float W11 = J11*R11 + J12*R21;
        const float W12 = J11*R12 + J12*R22;
        const float A00 = W00*S00 + W01*S01 + W02*S02;
        const float A01 = W00*S01 + W01*S11 + W02*S12;
        const float A02 = W00*S02 + W01*S12 + W02*S22;
        const float A10 = W10*S00 + W11*S01 + W12*S02;
        const float A11 = W10*S01 + W11*S11 + W12*S12;
        const float A12 = W10*S02 + W11*S12 + W12*S22;
        const float c00 = A00*W00 + A01*W01 + A02*W02;
        const float c01 = A00*W10 + A01*W11 + A02*W12;
        const float c10 = A10*W00 + A11*W01 + A12*W02;
        const float c11 = A10*W10 + A11*W11 + A12*W12;
        const float det = fmaxf(c00*c11 - c01*c10, 1e-12f);
        const float ia = c11 / det;
        const float ib = -c01 / det;
        const float ic = c00 / det;
        const float den = 2.0f * (float)M_PI * sqrtf(det);
        const float sig = 1.0f / (1.0f + expf(-f[7]));

        ws[rank]        = pu;
        ws[256 + rank]  = pv;
        ws[512 + rank]  = ia;
        ws[768 + rank]  = ib;
        ws[1024 + rank] = ic;
        ws[1280 + rank] = den;
        ws[1536 + rank] = sig;
        ((int*)ws)[1792 + rank] = t;

        // Conservative visibility: a >= 1/255 requires quad <= L.
        const float L = 2.0f * logf(sig * 255.0f / den);
        if (L > 0.0f) {
            const float qm = L + 0.02f;         // abs margin >> fp32 exp/log err
            const float detc = ia*ic - ib*ib;   // == 1/det (pos. definite)
            int wlo = 0, whi = Wd - 1, hlo = 0, hhi = Hd - 1;
            if (detc > 0.0f) {
                const float dxm = fminf(sqrtf(qm * ic / detc), 1.0e6f) + 1.0f;
                const float dym = fminf(sqrtf(qm * ia / detc), 1.0e6f) + 1.0f;
                wlo = max(0,      (int)floorf(pu - dxm - 0.5f));
                whi = min(Wd - 1, (int)ceilf (pu + dxm - 0.5f));
                hlo = max(0,      (int)floorf(pv - dym - 0.5f));
                hhi = min(Hd - 1, (int)ceilf (pv + dym - 0.5f));
            }
            if (wlo <= whi && hlo <= hhi) {
                const int tx0 = wlo >> 4, tx1 = whi >> 4;
                const int ty0 = hlo >> 4, ty1 = hhi >> 4;
                const unsigned long long bit = 1ULL << (rank & 63);
                const int word = rank >> 6;
                for (int ty = ty0; ty <= ty1; ++ty)
                    for (int tx = tx0; tx <= tx1; ++tx)
                        atomicOr(&masks[(ty * tilesX + tx) * 4 + word], bit);
            }
        }
    }
}

__global__ __launch_bounds__(256)
void raster_kernel(const float* __restrict__ feats,
                   const float* __restrict__ K,
                   const float* __restrict__ T,
                   const int* __restrict__ Hp,
                   const int* __restrict__ Wp,
                   const float* __restrict__ ws,
                   float* __restrict__ out) {
    __shared__ float lds[2048];
    __shared__ unsigned long long s_mask[4];

    const int t  = threadIdx.x;
    const int Wd = *Wp, Hd = *Hp;
    const int tilesX = (Wd + 15) >> 4;
    const int tilesY = (Hd + 15) >> 4;
    if ((int)blockIdx.x >= tilesX * tilesY) return;
    const int tileX = blockIdx.x % tilesX;
    const int tileY = blockIdx.x / tilesX;

    // Issue staging loads first; K^-1 / SH math below hides their latency.
    const float4 p0 = ((const float4*)ws)[t];
    const float4 p1 = ((const float4*)ws)[t + 256];
    unsigned long long mw = 0ULL;
    if (t < 4)
        mw = ((const unsigned long long*)(ws + 2048))[(size_t)blockIdx.x * 4 + t];

    const float R00 = T[0],  R01 = T[1],  R02 = T[2];
    const float R10 = T[4],  R11 = T[5],  R12 = T[6];
    const float R20 = T[8],  R21 = T[9],  R22 = T[10];

    const int wpx = tileX * 16 + (t & 15);
    const int hpx = tileY * 16 + (t >> 4);
    const bool valid = (wpx < Wd) && (hpx < Hd);

    // K^-1 via adjugate (matches jnp.linalg.inv; residual killed by normalize)
    const float k00 = K[0], k01 = K[1], k02 = K[2];
    const float k10 = K[3], k11 = K[4], k12 = K[5];
    const float k20 = K[6], k21 = K[7], k22 = K[8];
    const float d0 = k11*k22 - k12*k21;
    const float d1 = k12*k20 - k10*k22;
    const float d2 = k10*k21 - k11*k20;
    const float detK = k00*d0 + k01*d1 + k02*d2;
    const float i00 = d0/detK, i01 = (k02*k21 - k01*k22)/detK, i02 = (k01*k12 - k02*k11)/detK;
    const float i10 = d1/detK, i11 = (k00*k22 - k02*k20)/detK, i12 = (k02*k10 - k00*k12)/detK;
    const float i20 = d2/detK, i21 = (k01*k20 - k00*k21)/detK, i22 = (k00*k11 - k01*k10)/detK;

    const float uw = (float)wpx, vh = (float)hpx;
    const float cx0 = i00*uw + i01*vh + i02;
    const float cy0 = i10*uw + i11*vh + i12;
    const float cz0 = i20*uw + i21*vh + i22;
    float ddx = R00*cx0 + R10*cy0 + R20*cz0;
    float ddy = R01*cx0 + R11*cy0 + R21*cz0;
    float ddz = R02*cx0 + R12*cy0 + R22*cz0;
    const float nrm = sqrtf(ddx*ddx + ddy*ddy + ddz*ddz);
    const float x = ddx / nrm, y = ddy / nrm, z = ddz / nrm;
    const float xx = x*x, yy = y*y, zz = z*z;

    float sh[16];
    sh[0]  = 0.28209479177387814f;
    sh[1]  = -0.4886025119029199f * y;
    sh[2]  = 0.4886025119029199f * z;
    sh[3]  = -0.4886025119029199f * x;
    sh[4]  = 1.0925484305920792f * x * y;
    sh[5]  = -1.0925484305920792f * y * z;
    sh[6]  = 0.31539156525252005f * (2.0f*zz - xx - yy);
    sh[7]  = -1.0925484305920792f * x * z;
    sh[8]  = 0.5462742152960396f * (xx - yy);
    sh[9]  = -0.5900435899266435f * y * (3.0f*xx - yy);
    sh[10] = 2.890611442640554f * x * y * z;
    sh[11] = -0.4570457994644658f * y * (4.0f*zz - xx - yy);
    sh[12] = 0.3731763325901154f * z * (2.0f*zz - 3.0f*xx - 3.0f*yy);
    sh[13] = -0.4570457994644658f * x * (4.0f*zz - xx - yy);
    sh[14] = 1.445305721320277f * z * (xx - yy);
    sh[15] = -0.5900435899266435f * x * (xx - 3.0f*yy);

    // land staged data in LDS
    ((float4*)lds)[t]       = p0;
    ((float4*)lds)[t + 256] = p1;
    if (t < 4) s_mask[t] = mw;
    __syncthreads();

    const float* s_ux  = lds;
    const float* s_uy  = lds + 256;
    const float* s_ia  = lds + 512;
    const float* s_ib  = lds + 768;
    const float* s_ic  = lds + 1024;
    const float* s_den = lds + 1280;
    const float* s_sig = lds + 1536;
    const int*   s_gid = (const int*)(lds + 1792);

    const float pxc = uw + 0.5f;
    const float pyc = vh + 0.5f;
    float C = 0.0f;
    float img0 = 0.0f, img1 = 0.0f, img2 = 0.0f;

    #pragma unroll
    for (int wi = 0; wi < 4; ++wi) {
        unsigned long long m = s_mask[wi];
        while (m) {
            const int b = __ffsll(m) - 1;
            m &= m - 1;
            const int n = (wi << 6) + b;
            const float dx = s_ux[n] - pxc;
            const float dy = s_uy[n] - pyc;
            const float quad = s_ia[n]*dx*dx + s_ic[n]*dy*dy + 2.0f*s_ib[n]*dy*dx;
            const float g = expf(-0.5f * quad) / s_den[n];
            float a = g * s_sig[n];
            a = (a < ALPHA_SKIP) ? 0.0f : fminf(a, ALPHA_CLAMP);
            C += a;
            if (a > 0.0f && C <= ACC_BREAK) {
                const float wgt = a * (1.0f - (C - a));
                const float* cf = feats + 56*s_gid[n] + 8;
                float t0 = 0.0f, t1 = 0.0f, t2 = 0.0f;
                #pragma unroll
                for (int kk = 0; kk < 16; ++kk) {
                    const float bsh = sh[kk];
                    t0 += bsh * cf[kk];
                    t1 += bsh * cf[16 + kk];
                    t2 += bsh * cf[32 + kk];
                }
                img0 += wgt * (1.0f / (1.0f + expf(-t0)));
                img1 += wgt * (1.0f / (1.0f + expf(-t1)));
                img2 += wgt * (1.0f / (1.0f + expf(-t2)));
            }
        }
    }

    if (valid) {
        float* o = out + 3 * (hpx * Wd + wpx);
        o[0] = img0;
        o[1] = img1;
        o[2] = img2;
    }
}

extern "C" void kernel_launch(void* const* d_in, const int* in_sizes, int n_in,
                              void* d_out, int out_size, void* d_ws, size_t ws_size,
                              hipStream_t stream) {
    const float* pts   = (const float*)d_in[0];
    const float* feats = (const float*)d_in[1];
    const float* K     = (const float*)d_in[2];
    const float* T     = (const float*)d_in[3];
    const int*   Hp    = (const int*)d_in[4];
    const int*   Wp    = (const int*)d_in[5];
    float* ws  = (float*)d_ws;
    float* out = (float*)d_out;

    const int N = in_sizes[0] / 3;          // bench: 256
    const int npix = out_size / 3;          // bench: 65536
    const int blocks = (npix + 255) / 256;  // == tile count for W,H % 16 == 0

    prep_kernel<<<1, 256, 0, stream>>>(pts, feats, K, T, Hp, Wp, ws, N);
    raster_kernel<<<blocks, 256, 0, stream>>>(feats, K, T, Hp, Wp, ws, out);
}

// Round 5
// 11.092 us; speedup vs baseline: 1.8210x; 1.8210x over previous
//
#include <hip/hip_runtime.h>
#include <math.h>
#include <float.h>

#define NEAR_PLANE 0.8f
#define FAR_PLANE 1000.0f
#define ALPHA_SKIP (1.0f/255.0f)
#define ALPHA_CLAMP 0.99f
#define ACC_BREAK 0.9999f

// Single fused kernel, one 16x16 tile per block, NO global sort.
//
// Per block: thread t projects gaussian t, computes its conic, and tests a
// conservative ALPHA_SKIP ellipse bbox (quad <= 2*ln(255*sig/den) + margin)
// against this tile. __ballot -> 256-bit coverage mask -> popcount-prefix
// compaction of the covering set (typically ~10 gaussians), then a rank sort
// WITHIN the covering set only (each covering thread scans K LDS entries,
// tie-break on original index == stable jnp.argsort), scattering its
// register-held raster params to the depth-sorted slot. The raster loop walks
// the dense sorted array front-to-back.
//
// Correctness: gaussians outside the conservative bbox have a < 1/255 at
// every pixel of this tile -> contribute exactly 0.0f to the reference's
// cumulative sum; the covering subset in (zc, idx) order equals the global
// stable sort restricted to the subset. Output is bit-identical to the dense
// reference loop. Assumes N <= 256 (bench: 256), W,H % 16 == 0 (bench: 256).
__global__ __launch_bounds__(256)
void fused_raster(const float* __restrict__ pts,
                  const float* __restrict__ feats,
                  const float* __restrict__ K,
                  const float* __restrict__ T,
                  const int* __restrict__ Hp,
                  const int* __restrict__ Wp,
                  float* __restrict__ out,
                  int N) {
    __shared__ unsigned long long s_mask[4];
    __shared__ float c_key[256];
    __shared__ int   c_id[256];
    __shared__ float r_ux[256], r_uy[256];
    __shared__ float r_ia[256], r_ib[256], r_ic[256];
    __shared__ float r_den[256], r_sig[256];
    __shared__ int   r_gid[256];

    const int t  = threadIdx.x;
    const int Wd = *Wp, Hd = *Hp;
    const int tilesX = (Wd + 15) >> 4;
    const int tilesY = (Hd + 15) >> 4;
    if ((int)blockIdx.x >= tilesX * tilesY) return;
    const int tileX = blockIdx.x % tilesX;
    const int tileY = blockIdx.x / tilesX;

    const float R00 = T[0],  R01 = T[1],  R02 = T[2],  ttx = T[3];
    const float R10 = T[4],  R11 = T[5],  R12 = T[6],  tty = T[7];
    const float R20 = T[8],  R21 = T[9],  R22 = T[10], ttz = T[11];

    // ---- phase 1: project + conic + tile-cull for own gaussian ----
    float key = FLT_MAX;
    float pu = 0.f, pv = 0.f;
    float ia = 0.f, ib = 0.f, ic = 0.f, den = 1.f, sig = 0.f;
    bool cover = false;
    if (t < N) {
        const float px = pts[3*t], py = pts[3*t+1], pz = pts[3*t+2];
        const float cxv = R00*px + R01*py + R02*pz + ttx;
        const float cyv = R10*px + R11*py + R12*pz + tty;
        const float czv = R20*px + R21*py + R22*pz + ttz;
        const float zc = czv;
        const float denom = fmaxf(zc, 1e-6f);
        const float K00 = K[0], K01 = K[1], K02 = K[2];
        const float K10 = K[3], K11 = K[4], K12 = K[5];
        pu = (K00*cxv + K01*cyv + K02*czv) / denom;
        pv = (K10*cxv + K11*cyv + K12*czv) / denom;
        const bool in_cam = (zc > NEAR_PLANE) && (zc < FAR_PLANE) &&
                            (pu >= 0.0f) && (pu < (float)Wd) &&
                            (pv >= 0.0f) && (pv < (float)Hd);
        key = in_cam ? zc : 1e10f;

        if (in_cam) {
            const float* f = feats + 56*t;
            const float4 fq = *(const float4*)f;        // quat
            const float4 fs = *(const float4*)(f + 4);  // log_s, alpha
            float qx = fq.x, qy = fq.y, qz = fq.z, qw = fq.w;
            const float qn = sqrtf(qx*qx + qy*qy + qz*qz + qw*qw);
            qx /= qn; qy /= qn; qz /= qn; qw /= qn;
            const float Q00 = 1.0f - 2.0f*(qy*qy + qz*qz);
            const float Q01 = 2.0f*(qx*qy - qz*qw);
            const float Q02 = 2.0f*(qx*qz + qy*qw);
            const float Q10 = 2.0f*(qx*qy + qz*qw);
            const float Q11 = 1.0f - 2.0f*(qx*qx + qz*qz);
            const float Q12 = 2.0f*(qy*qz - qx*qw);
            const float Q20 = 2.0f*(qx*qz - qy*qw);
            const float Q21 = 2.0f*(qy*qz + qx*qw);
            const float Q22 = 1.0f - 2.0f*(qx*qx + qy*qy);
            const float s0 = expf(fs.x), s1 = expf(fs.y), s2 = expf(fs.z);
            const float M00 = Q00*s0, M01 = Q01*s1, M02 = Q02*s2;
            const float M10 = Q10*s0, M11 = Q11*s1, M12 = Q12*s2;
            const float M20 = Q20*s0, M21 = Q21*s1, M22 = Q22*s2;
            const float S00 = M00*M00 + M01*M01 + M02*M02;
            const float S01 = M00*M10 + M01*M11 + M02*M12;
            const float S02 = M00*M20 + M01*M21 + M02*M22;
            const float S11 = M10*M10 + M11*M11 + M12*M12;
            const float S12 = M10*M20 + M11*M21 + M12*M22;
            const float S22 = M20*M20 + M21*M21 + M22*M22;

            const float fx = K00, fy = K11;
            const float J00 = fx / czv;
            const float J02 = -fx * cxv / (czv * czv);
            const float J11 = fy / czv;
            const float J12 = -fy * cyv / (czv * czv);
            const float W00 = J00*R00 + J02*R20;
            const float W01 = J00*R01 + J02*R21;
            const float W02 = J00*R02 + J02*R22;
            const float W10 = J11*R10 + J12*R20;
            const float W11 = J11*R11 + J12*R21;
            const float W12 = J11*R12 + J12*R22;
            const float A00 = W00*S00 + W01*S01 + W02*S02;
            const float A01 = W00*S01 + W01*S11 + W02*S12;
            const float A02 = W00*S02 + W01*S12 + W02*S22;
            const float A10 = W10*S00 + W11*S01 + W12*S02;
            const float A11 = W10*S01 + W11*S11 + W12*S12;
            const float A12 = W10*S02 + W11*S12 + W12*S22;
            const float c00 = A00*W00 + A01*W01 + A02*W02;
            const float c01 = A00*W10 + A01*W11 + A02*W12;
            const float c10 = A10*W00 + A11*W01 + A12*W02;
            const float c11 = A10*W10 + A11*W11 + A12*W12;
            const float det = fmaxf(c00*c11 - c01*c10, 1e-12f);
            ia = c11 / det;
            ib = -c01 / det;
            ic = c00 / det;
            den = 2.0f * (float)M_PI * sqrtf(det);
            sig = 1.0f / (1.0f + expf(-fs.w));

            // Conservative visibility: a >= 1/255 requires quad <= L.
            const float L = 2.0f * logf(sig * 255.0f / den);
            if (L > 0.0f) {
                const float qm = L + 0.02f;        // margin >> fp32 exp/log err
                const float detc = ia*ic - ib*ib;  // == 1/det (pos. definite)
                int wlo = 0, whi = Wd - 1, hlo = 0, hhi = Hd - 1;
                if (detc > 0.0f) {
                    const float dxm = fminf(sqrtf(qm * ic / detc), 1.0e6f) + 1.0f;
                    const float dym = fminf(sqrtf(qm * ia / detc), 1.0e6f) + 1.0f;
                    wlo = max(0,      (int)floorf(pu - dxm - 0.5f));
                    whi = min(Wd - 1, (int)ceilf (pu + dxm - 0.5f));
                    hlo = max(0,      (int)floorf(pv - dym - 0.5f));
                    hhi = min(Hd - 1, (int)ceilf (pv + dym - 0.5f));
                }
                if (wlo <= whi && hlo <= hhi) {
                    const int tx0 = wlo >> 4, tx1 = whi >> 4;
                    const int ty0 = hlo >> 4, ty1 = hhi >> 4;
                    cover = (tileX >= tx0) && (tileX <= tx1) &&
                            (tileY >= ty0) && (tileY <= ty1);
                }
            }
        }
    }

    // ---- phase 2: ballot + compact covering set ----
    const unsigned long long bb = __ballot(cover);
    if ((t & 63) == 0) s_mask[t >> 6] = bb;
    __syncthreads();

    const int wi = t >> 6;
    const int lane = t & 63;
    int Kc = 0, base = 0;
    #pragma unroll
    for (int w = 0; w < 4; ++w) {
        const int pc = __popcll(s_mask[w]);
        if (w < wi) base += pc;
        Kc += pc;
    }
    const int p = base + __popcll(bb & ((1ULL << lane) - 1ULL));
    if (cover) { c_key[p] = key; c_id[p] = t; }
    __syncthreads();

    // ---- phase 3: rank within covering set, scatter params to sorted slot ----
    if (cover) {
        int rank = 0;
        for (int j = 0; j < Kc; ++j) {
            const float kj = c_key[j];
            rank += (int)((kj < key) || (kj == key && c_id[j] < t));
        }
        r_ux[rank] = pu;  r_uy[rank] = pv;
        r_ia[rank] = ia;  r_ib[rank] = ib;  r_ic[rank] = ic;
        r_den[rank] = den; r_sig[rank] = sig;
        r_gid[rank] = t;
    }
    __syncthreads();

    // ---- phase 4: rasterize this tile's pixels ----
    const int wpx = tileX * 16 + (t & 15);
    const int hpx = tileY * 16 + (t >> 4);
    const bool valid = (wpx < Wd) && (hpx < Hd);

    // K^-1 via adjugate (matches jnp.linalg.inv; residual killed by normalize)
    const float k00 = K[0], k01 = K[1], k02 = K[2];
    const float k10 = K[3], k11 = K[4], k12 = K[5];
    const float k20 = K[6], k21 = K[7], k22 = K[8];
    const float d0 = k11*k22 - k12*k21;
    const float d1 = k12*k20 - k10*k22;
    const float d2 = k10*k21 - k11*k20;
    const float detK = k00*d0 + k01*d1 + k02*d2;
    const float i00 = d0/detK, i01 = (k02*k21 - k01*k22)/detK, i02 = (k01*k12 - k02*k11)/detK;
    const float i10 = d1/detK, i11 = (k00*k22 - k02*k20)/detK, i12 = (k02*k10 - k00*k12)/detK;
    const float i20 = d2/detK, i21 = (k01*k20 - k00*k21)/detK, i22 = (k00*k11 - k01*k10)/detK;

    const float uw = (float)wpx, vh = (float)hpx;
    const float cx0 = i00*uw + i01*vh + i02;
    const float cy0 = i10*uw + i11*vh + i12;
    const float cz0 = i20*uw + i21*vh + i22;
    float ddx = R00*cx0 + R10*cy0 + R20*cz0;
    float ddy = R01*cx0 + R11*cy0 + R21*cz0;
    float ddz = R02*cx0 + R12*cy0 + R22*cz0;
    const float nrm = sqrtf(ddx*ddx + ddy*ddy + ddz*ddz);
    const float x = ddx / nrm, y = ddy / nrm, z = ddz / nrm;
    const float xx = x*x, yy = y*y, zz = z*z;

    float sh[16];
    sh[0]  = 0.28209479177387814f;
    sh[1]  = -0.4886025119029199f * y;
    sh[2]  = 0.4886025119029199f * z;
    sh[3]  = -0.4886025119029199f * x;
    sh[4]  = 1.0925484305920792f * x * y;
    sh[5]  = -1.0925484305920792f * y * z;
    sh[6]  = 0.31539156525252005f * (2.0f*zz - xx - yy);
    sh[7]  = -1.0925484305920792f * x * z;
    sh[8]  = 0.5462742152960396f * (xx - yy);
    sh[9]  = -0.5900435899266435f * y * (3.0f*xx - yy);
    sh[10] = 2.890611442640554f * x * y * z;
    sh[11] = -0.4570457994644658f * y * (4.0f*zz - xx - yy);
    sh[12] = 0.3731763325901154f * z * (2.0f*zz - 3.0f*xx - 3.0f*yy);
    sh[13] = -0.4570457994644658f * x * (4.0f*zz - xx - yy);
    sh[14] = 1.445305721320277f * z * (xx - yy);
    sh[15] = -0.5900435899266435f * x * (xx - 3.0f*yy);

    const float pxc = uw + 0.5f;
    const float pyc = vh + 0.5f;
    float C = 0.0f;
    float img0 = 0.0f, img1 = 0.0f, img2 = 0.0f;

    for (int n = 0; n < Kc; ++n) {
        const float dx = r_ux[n] - pxc;
        const float dy = r_uy[n] - pyc;
        const float quad = r_ia[n]*dx*dx + r_ic[n]*dy*dy + 2.0f*r_ib[n]*dy*dx;
        const float g = expf(-0.5f * quad) / r_den[n];
        float a = g * r_sig[n];
        a = (a < ALPHA_SKIP) ? 0.0f : fminf(a, ALPHA_CLAMP);
        C += a;
        if (a > 0.0f && C <= ACC_BREAK) {
            const float wgt = a * (1.0f - (C - a));
            const float* cf = feats + 56*r_gid[n] + 8;
            float t0 = 0.0f, t1 = 0.0f, t2 = 0.0f;
            #pragma unroll
            for (int kk = 0; kk < 16; ++kk) {
                const float bsh = sh[kk];
                t0 += bsh * cf[kk];
                t1 += bsh * cf[16 + kk];
                t2 += bsh * cf[32 + kk];
            }
            img0 += wgt * (1.0f / (1.0f + expf(-t0)));
            img1 += wgt * (1.0f / (1.0f + expf(-t1)));
            img2 += wgt * (1.0f / (1.0f + expf(-t2)));
        }
    }

    if (valid) {
        float* o = out + 3 * (hpx * Wd + wpx);
        o[0] = img0;
        o[1] = img1;
        o[2] = img2;
    }
}

extern "C" void kernel_launch(void* const* d_in, const int* in_sizes, int n_in,
                              void* d_out, int out_size, void* d_ws, size_t ws_size,
                              hipStream_t stream) {
    const float* pts   = (const float*)d_in[0];
    const float* feats = (const float*)d_in[1];
    const float* K     = (const float*)d_in[2];
    const float* T     = (const float*)d_in[3];
    const int*   Hp    = (const int*)d_in[4];
    const int*   Wp    = (const int*)d_in[5];
    float* out = (float*)d_out;

    const int N = in_sizes[0] / 3;          // bench: 256
    const int npix = out_size / 3;          // bench: 65536
    const int blocks = (npix + 255) / 256;  // == tile count for W,H % 16 == 0

    fused_raster<<<blocks, 256, 0, stream>>>(pts, feats, K, T, Hp, Wp, out, N);
}